// Round 5
// baseline (769.895 us; speedup 1.0000x reference)
//
#include <hip/hip_runtime.h>

#define NN 10000
#define NE 320000
#define NG 64
#define D1 128
#define D2 256

typedef unsigned short u16;
typedef short v8s __attribute__((ext_vector_type(8)));
typedef float v4f __attribute__((ext_vector_type(4)));

__device__ __forceinline__ u16 f2bf(float x) {
    unsigned u = __float_as_uint(x);
    return (u16)((u + 0x7fffu + ((u >> 16) & 1u)) >> 16);
}
__device__ __forceinline__ float bf2f(u16 b) {
    return __uint_as_float(((unsigned)b) << 16);
}

// async global->LDS, 16B per lane; LDS dest = wave-uniform base + lane*16
#define GLDS16(gp, lp)                                                         \
    __builtin_amdgcn_global_load_lds(                                          \
        (__attribute__((address_space(1))) unsigned int*)(unsigned long long)(gp), \
        (__attribute__((address_space(3))) unsigned int*)(lp), 16, 0, 0)

// =====================================================================
// Split-bf16 MFMA GEMM, double-buffered LDS.
// D[M,N] = (Ah+Al)[M,K] @ (Bh+Bl)[N,K]^T ; 128x128 tile, 4 waves,
// 64x64/wave, 16x16x32 mfma, BK=32, 3 mfma/frag pair (drop lo*lo).
// Pipeline: barrier -> issue stage(k+1) into other buffer -> compute(k).
// The barrier's vmcnt(0) drain then waits on loads issued one full
// compute phase earlier (latency hidden), not just-issued ones.
// SPLIT: cols < N0 -> Cm (stride N0, no bias); cols >= N0 -> Cg
// (stride N-N0, +bias[gc-N0]). N0 multiple of 128 (block-uniform).
// =====================================================================
template<bool SPLIT>
__global__ __launch_bounds__(256)
void mgemm_k(const u16* __restrict__ Ah, const u16* __restrict__ Al,
             const u16* __restrict__ Bh, const u16* __restrict__ Bl,
             const float* __restrict__ bias, float* __restrict__ Cm,
             float* __restrict__ Cg, int M, int N, int K, int N0) {
    __shared__ u16 lds[32768];  // 2 buffers x 16384 u16 (32 KB each)
    const int tid = threadIdx.x;
    const int wave = tid >> 6, lane = tid & 63;
    const int wm = (wave >> 1) * 64, wn = (wave & 1) * 64;
    const int bm = blockIdx.y * 128, bn = blockIdx.x * 128;
    const int quad = lane >> 4, r16 = lane & 15;

    auto stage = [&](int k0, int buf) {
#pragma unroll
        for (int j = 0; j < 2; ++j) {
            int row = j * 64 + lane;
            size_t aoff = (size_t)(bm + row) * K + k0 + wave * 8;
            size_t boff = (size_t)(bn + row) * K + k0 + wave * 8;
            int s = buf * 16384 + (wave * 128 + j * 64) * 8;
            GLDS16(Ah + aoff, &lds[s]);
            GLDS16(Al + aoff, &lds[4096 + s]);
            GLDS16(Bh + boff, &lds[8192 + s]);
            GLDS16(Bl + boff, &lds[12288 + s]);
        }
    };

    v4f acc[4][4] = {};
    stage(0, 0);
    int cur = 0;
    for (int k0 = 0; k0 < K; k0 += 32) {
        __syncthreads();  // drains stage(k0) [issued last iter] + guards reuse
        if (k0 + 32 < K) stage(k0 + 32, cur ^ 1);

        v8s ah[4], al[4], bh[4], bl[4];
        const int base = cur * 16384;
#pragma unroll
        for (int i = 0; i < 4; ++i) {
            int ra = base + (quad * 128 + wm + i * 16 + r16) * 8;
            int rb = base + (quad * 128 + wn + i * 16 + r16) * 8;
            ah[i] = *(const v8s*)&lds[ra];
            al[i] = *(const v8s*)&lds[4096 + ra];
            bh[i] = *(const v8s*)&lds[8192 + rb];
            bl[i] = *(const v8s*)&lds[12288 + rb];
        }
#pragma unroll
        for (int i = 0; i < 4; ++i)
#pragma unroll
            for (int j = 0; j < 4; ++j) {
                acc[i][j] = __builtin_amdgcn_mfma_f32_16x16x32_bf16(ah[i], bh[j], acc[i][j], 0, 0, 0);
                acc[i][j] = __builtin_amdgcn_mfma_f32_16x16x32_bf16(ah[i], bl[j], acc[i][j], 0, 0, 0);
                acc[i][j] = __builtin_amdgcn_mfma_f32_16x16x32_bf16(al[i], bh[j], acc[i][j], 0, 0, 0);
            }
        cur ^= 1;
    }

    // epilogue: C/D layout col=lane&15, row=quad*4+reg
#pragma unroll
    for (int i = 0; i < 4; ++i) {
        int gr0 = bm + wm + i * 16 + quad * 4;
#pragma unroll
        for (int j = 0; j < 4; ++j) {
            int gc = bn + wn + j * 16 + r16;
            if (SPLIT && gc < N0) {  // block-uniform branch
#pragma unroll
                for (int r = 0; r < 4; ++r) {
                    int gr = gr0 + r;
                    if (gr < M) Cm[(size_t)gr * N0 + gc] = acc[i][j][r];
                }
            } else {
                int cc = SPLIT ? gc - N0 : gc;
                int ns = SPLIT ? N - N0 : N;
                float bv = bias[cc];
#pragma unroll
                for (int r = 0; r < 4; ++r) {
                    int gr = gr0 + r;
                    if (gr < M) Cg[(size_t)gr * ns + cc] = acc[i][j][r] + bv;
                }
            }
        }
    }
}

// =====================================================================
// CSR build
// =====================================================================
__global__ void count_k(const int* __restrict__ dst, int* __restrict__ cnt) {
    int e = blockIdx.x * blockDim.x + threadIdx.x;
    if (e < NE) atomicAdd(&cnt[dst[e]], 1);
}

__global__ void scan_k(const int* __restrict__ cnt, int* __restrict__ off,
                       int* __restrict__ cur) {
    __shared__ int ps[1024];
    const int tid = threadIdx.x;
    const int CH = (NN + 1023) / 1024;
    const int base = tid * CH;
    int s = 0;
    for (int i = 0; i < CH; ++i) {
        int idx = base + i;
        if (idx < NN) s += cnt[idx];
    }
    ps[tid] = s;
    __syncthreads();
    for (int d = 1; d < 1024; d <<= 1) {
        int v = (tid >= d) ? ps[tid - d] : 0;
        __syncthreads();
        ps[tid] += v;
        __syncthreads();
    }
    int run = (tid > 0) ? ps[tid - 1] : 0;
    for (int i = 0; i < CH; ++i) {
        int idx = base + i;
        if (idx <= NN) { off[idx] = run; if (idx < NN) cur[idx] = run; }
        if (idx < NN) run += cnt[idx];
    }
}

__global__ void fill_k(const int* __restrict__ src, const int* __restrict__ dst,
                       int* __restrict__ cur, int* __restrict__ elist) {
    int e = blockIdx.x * blockDim.x + threadIdx.x;
    if (e >= NE) return;
    int p = atomicAdd(&cur[dst[e]], 1);
    elist[p] = src[e];
}

// =====================================================================
// CSR gather, 4-deep software pipeline: a[n,:] = sum m[src,:], bf16 hi/lo out
// =====================================================================
template<int C>
__global__ void gather_k(const float* __restrict__ m, const int* __restrict__ off,
                         const int* __restrict__ elist,
                         u16* __restrict__ ah, u16* __restrict__ al) {
    constexpr int LPN = C / 4;
    int t = blockIdx.x * blockDim.x + threadIdx.x;
    int node = t / LPN;
    if (node >= NN) return;
    int c = (t % LPN) * 4;
    int s0 = off[node], s1 = off[node + 1];
    v4f a0 = 0.f, a1 = 0.f, a2 = 0.f, a3 = 0.f;
    int i = s0;
    for (; i + 4 <= s1; i += 4) {
        int e0 = elist[i], e1 = elist[i + 1], e2 = elist[i + 2], e3 = elist[i + 3];
        v4f v0 = *(const v4f*)(m + (size_t)e0 * C + c);
        v4f v1 = *(const v4f*)(m + (size_t)e1 * C + c);
        v4f v2 = *(const v4f*)(m + (size_t)e2 * C + c);
        v4f v3 = *(const v4f*)(m + (size_t)e3 * C + c);
        a0 += v0; a1 += v1; a2 += v2; a3 += v3;
    }
    for (; i < s1; ++i) {
        int e = elist[i];
        a0 += *(const v4f*)(m + (size_t)e * C + c);
    }
    v4f acc = (a0 + a1) + (a2 + a3);
    ushort4 h, l;
    h.x = f2bf(acc.x); l.x = f2bf(acc.x - bf2f(h.x));
    h.y = f2bf(acc.y); l.y = f2bf(acc.y - bf2f(h.y));
    h.z = f2bf(acc.z); l.z = f2bf(acc.z - bf2f(h.z));
    h.w = f2bf(acc.w); l.w = f2bf(acc.w - bf2f(h.w));
    *(ushort4*)(ah + (size_t)node * C + c) = h;
    *(ushort4*)(al + (size_t)node * C + c) = l;
}

// =====================================================================
// GRU gates. MODE 0: x = (1-z)*n + z*h in place (stride C) + bf16 hi/lo.
// MODE 1 (layer-1 final, C=128): out = relu(gru), padded to 256 cols;
//        writes x2 + xh/xl (stride 256). Grid NN*64; q>=32 writes zeros.
// MODE 2 (layer-2 final, C=256): no stores of x; atomicMax monotone-mapped
//        result into pool[batch[n]*256+c]. Grid NN*64.
// =====================================================================
template<int C, int MODE>
__global__ void gates_k(const float* __restrict__ gi, const float* __restrict__ gh,
                        const float* __restrict__ xin, float* __restrict__ xout,
                        u16* __restrict__ xh, u16* __restrict__ xl,
                        const int* __restrict__ batch, unsigned* __restrict__ pool) {
    constexpr int Q = C / 4;                      // input-side float4 count
    constexpr int QO = (MODE == 0) ? Q : 64;      // thread q-range
    int t = blockIdx.x * blockDim.x + threadIdx.x;
    if (t >= NN * QO) return;
    int n = t / QO, q = t - n * QO;

    if (MODE == 1 && q >= Q) {  // pad region: zeros
        ushort4 z4 = {0, 0, 0, 0};
        ((float4*)(xout + (size_t)n * 256))[q] = make_float4(0.f, 0.f, 0.f, 0.f);
        *(ushort4*)(xh + (size_t)n * 256 + q * 4) = z4;
        *(ushort4*)(xl + (size_t)n * 256 + q * 4) = z4;
        return;
    }

    const float4* gin = (const float4*)(gi + (size_t)n * 3 * C);
    const float4* ghn = (const float4*)(gh + (size_t)n * 3 * C);
    float4 ir = gin[q], iz = gin[Q + q], in_ = gin[2 * Q + q];
    float4 hr = ghn[q], hz = ghn[Q + q], hn = ghn[2 * Q + q];
    float4 h = ((const float4*)(xin + (size_t)n * C))[q];
    float4 o;
#define GRU1(f)                                                       \
    {                                                                 \
        float r = 1.f / (1.f + expf(-(ir.f + hr.f)));                 \
        float z = 1.f / (1.f + expf(-(iz.f + hz.f)));                 \
        float nn_ = tanhf(in_.f + r * hn.f);                          \
        o.f = (1.f - z) * nn_ + z * h.f;                              \
    }
    GRU1(x) GRU1(y) GRU1(z) GRU1(w)
#undef GRU1

    if (MODE == 2) {
        int pb = batch[n] * 256 + q * 4;
#define PMAX(f, k)                                                    \
        {                                                             \
            unsigned b = __float_as_uint(o.f);                        \
            unsigned u = (b & 0x80000000u) ? ~b : (b | 0x80000000u);  \
            atomicMax(&pool[pb + k], u);                              \
        }
        PMAX(x, 0) PMAX(y, 1) PMAX(z, 2) PMAX(w, 3)
#undef PMAX
        return;
    }

    if (MODE == 1) { o.x = fmaxf(o.x, 0.f); o.y = fmaxf(o.y, 0.f);
                     o.z = fmaxf(o.z, 0.f); o.w = fmaxf(o.w, 0.f); }
    constexpr int OS = (MODE == 1) ? 256 : C;  // output row stride
    ((float4*)(xout + (size_t)n * OS))[q] = o;
    ushort4 hh, ll;
    hh.x = f2bf(o.x); ll.x = f2bf(o.x - bf2f(hh.x));
    hh.y = f2bf(o.y); ll.y = f2bf(o.y - bf2f(hh.y));
    hh.z = f2bf(o.z); ll.z = f2bf(o.z - bf2f(hh.z));
    hh.w = f2bf(o.w); ll.w = f2bf(o.w - bf2f(hh.w));
    *(ushort4*)(xh + (size_t)n * OS + q * 4) = hh;
    *(ushort4*)(xl + (size_t)n * OS + q * 4) = ll;
}

// =====================================================================
// prep_k: all weight conversions + x-init in one launch.
// B1cat[it] = [512,128]:  rows 0..127 = w1[it]^T, rows 128..511 = whh1
// B2cat[it] = [1024,256]: rows 0..255 = w2[it]^T, rows 256..1023 = whh2
// =====================================================================
__global__ void prep_k(const float* __restrict__ w1, const float* __restrict__ whh1,
                       const float* __restrict__ wih1, const float* __restrict__ w2,
                       const float* __restrict__ whh2, const float* __restrict__ wih2,
                       const float* __restrict__ xin,
                       u16* __restrict__ B1h, u16* __restrict__ B1l,
                       u16* __restrict__ B2h, u16* __restrict__ B2l,
                       u16* __restrict__ wih1h, u16* __restrict__ wih1l,
                       u16* __restrict__ wih2h, u16* __restrict__ wih2l,
                       float* __restrict__ x1, u16* __restrict__ xh,
                       u16* __restrict__ xl) {
    const int n1 = 3 * D1 * D1, n2 = 3 * D2 * D2;
    int t = blockIdx.x * blockDim.x + threadIdx.x;
    if (t < n1) {  // w1 transpose
        int l = t / (D1 * D1), rem = t - l * D1 * D1;
        int k = rem / D1, n = rem - k * D1;
        float v = w1[t]; u16 h = f2bf(v), lo = f2bf(v - bf2f(h));
        int o = (l * 512 + n) * D1 + k;
        B1h[o] = h; B1l[o] = lo; return;
    }
    t -= n1;
    if (t < n1) {  // whh1 replicate x3
        float v = whh1[t]; u16 h = f2bf(v), lo = f2bf(v - bf2f(h));
        int r = t / D1, k = t - r * D1;
#pragma unroll
        for (int l = 0; l < 3; ++l) {
            int o = (l * 512 + 128 + r) * D1 + k;
            B1h[o] = h; B1l[o] = lo;
        }
        return;
    }
    t -= n1;
    if (t < n2) {  // w2 transpose
        int l = t / (D2 * D2), rem = t - l * D2 * D2;
        int k = rem / D2, n = rem - k * D2;
        float v = w2[t]; u16 h = f2bf(v), lo = f2bf(v - bf2f(h));
        int o = (l * 1024 + n) * D2 + k;
        B2h[o] = h; B2l[o] = lo; return;
    }
    t -= n2;
    if (t < n2) {  // whh2 replicate x3
        float v = whh2[t]; u16 h = f2bf(v), lo = f2bf(v - bf2f(h));
        int r = t / D2, k = t - r * D2;
#pragma unroll
        for (int l = 0; l < 3; ++l) {
            int o = (l * 1024 + 256 + r) * D2 + k;
            B2h[o] = h; B2l[o] = lo;
        }
        return;
    }
    t -= n2;
    if (t < n1) { float v = wih1[t]; u16 h = f2bf(v); wih1h[t] = h; wih1l[t] = f2bf(v - bf2f(h)); return; }
    t -= n1;
    if (t < n2) { float v = wih2[t]; u16 h = f2bf(v); wih2h[t] = h; wih2l[t] = f2bf(v - bf2f(h)); return; }
    t -= n2;
    if (t < NN * D1) {  // x init
        float v = xin[t];
        x1[t] = v;
        u16 h = f2bf(v);
        xh[t] = h;
        xl[t] = f2bf(v - bf2f(h));
    }
}

__global__ void pool_init_k(unsigned* __restrict__ pool) {
    int t = blockIdx.x * blockDim.x + threadIdx.x;
    if (t < NG * D2) pool[t] = 0x007FFFFFu;  // mapped(-inf)
}

__global__ void fc_k(const unsigned* __restrict__ pool, const float* __restrict__ w,
                     const float* __restrict__ b, float* __restrict__ out) {
    int t = blockIdx.x * blockDim.x + threadIdx.x;
    if (t >= NG * 6) return;
    int g = t / 6, o = t - g * 6;
    float s = b[o];
    for (int c = 0; c < D2; ++c) {
        unsigned u = pool[g * D2 + c];
        unsigned bits = (u & 0x80000000u) ? (u ^ 0x80000000u) : ~u;
        s += __uint_as_float(bits) * w[o * D2 + c];
    }
    out[t] = s;
}

// =======================================================================
extern "C" void kernel_launch(void* const* d_in, const int* in_sizes, int n_in,
                              void* d_out, int out_size, void* d_ws, size_t ws_size,
                              hipStream_t stream) {
    const float* x_in = (const float*)d_in[0];
    const int* ei = (const int*)d_in[1];
    const int* src = ei;
    const int* dst = ei + NE;
    const int* batch = (const int*)d_in[2];
    const float* w1   = (const float*)d_in[3];
    const float* wih1 = (const float*)d_in[4];
    const float* whh1 = (const float*)d_in[5];
    const float* bih1 = (const float*)d_in[6];
    const float* bhh1 = (const float*)d_in[7];
    const float* w2   = (const float*)d_in[8];
    const float* wih2 = (const float*)d_in[9];
    const float* whh2 = (const float*)d_in[10];
    const float* bih2 = (const float*)d_in[11];
    const float* bhh2 = (const float*)d_in[12];
    const float* fcw  = (const float*)d_in[13];
    const float* fcb  = (const float*)d_in[14];
    float* out = (float*)d_out;

    // ---- workspace layout ----
    // mbuf aliases gibuf: fused GEMM writes m -> gather reads m, writes a_hl
    // -> gi GEMM overwrites gibuf (m dead, reads a_hl). gh separate.
    float* ws = (float*)d_ws;
    float* gibuf = ws;                        // [NN,768] fp32
    float* mbuf  = gibuf;                     // alias [NN,<=256] fp32
    float* ghbuf = gibuf + NN * 768;          // [NN,768] fp32
    u16* a_h = (u16*)(ghbuf + NN * 768);      // [NN,256] bf16
    u16* a_l = a_h + NN * 256;
    float* x1 = (float*)(a_l + NN * 256);     // [NN,128] fp32
    float* x2 = x1 + NN * 128;                // [NN,256] fp32
    u16* x_h = (u16*)(x2 + NN * 256);         // [NN,256] bf16 (layer1 stride 128)
    u16* x_l = x_h + NN * 256;
    u16* B1h = x_l + NN * 256;                // [3][512][128]
    u16* B1l = B1h + 3 * 512 * D1;
    u16* B2h = B1l + 3 * 512 * D1;            // [3][1024][256]
    u16* B2l = B2h + 3 * 1024 * D2;
    u16* wih1h = B2l + 3 * 1024 * D2;         // [384,128]
    u16* wih1l = wih1h + 3 * D1 * D1;
    u16* wih2h = wih1l + 3 * D1 * D1;         // [768,256]
    u16* wih2l = wih2h + 3 * D2 * D2;
    int* cnt   = (int*)(wih2l + 3 * D2 * D2);
    int* off   = cnt + NN;
    int* cur   = off + NN + 1;
    int* elist = cur + NN;
    unsigned* pool = (unsigned*)(elist + NE);

    // ---- CSR build + prep + pool init ----
    hipMemsetAsync(cnt, 0, NN * sizeof(int), stream);
    count_k<<<(NE + 255) / 256, 256, 0, stream>>>(dst, cnt);
    scan_k<<<1, 1024, 0, stream>>>(cnt, off, cur);
    fill_k<<<(NE + 255) / 256, 256, 0, stream>>>(src, dst, cur, elist);
    {
        int total = 3 * (3 * D1 * D1) + 3 * (3 * D2 * D2) + NN * D1;
        prep_k<<<(total + 255) / 256, 256, 0, stream>>>(
            w1, whh1, wih1, w2, whh2, wih2, x_in,
            B1h, B1l, B2h, B2l, wih1h, wih1l, wih2h, wih2l, x1, x_h, x_l);
    }
    pool_init_k<<<(NG * D2 + 255) / 256, 256, 0, stream>>>(pool);

    const int MT = (NN + 127) / 128;  // 79

    // ---------------- layer 1 (C = 128) ----------------
    for (int it = 0; it < 3; ++it) {
        const int C = D1;
        mgemm_k<true><<<dim3(4 * C / 128, MT), 256, 0, stream>>>(
            x_h, x_l, B1h + it * 512 * C, B1l + it * 512 * C,
            bhh1, mbuf, ghbuf, NN, 4 * C, C, C);
        gather_k<D1><<<(NN * (D1 / 4) + 255) / 256, 256, 0, stream>>>(
            mbuf, off, elist, a_h, a_l);
        mgemm_k<false><<<dim3(3 * C / 128, MT), 256, 0, stream>>>(
            a_h, a_l, wih1h, wih1l, bih1, nullptr, gibuf, NN, 3 * C, C, 0);
        if (it < 2)
            gates_k<D1, 0><<<(NN * 32 + 255) / 256, 256, 0, stream>>>(
                gibuf, ghbuf, x1, x1, x_h, x_l, nullptr, nullptr);
        else  // fused relu+pad -> x2 (stride 256)
            gates_k<D1, 1><<<(NN * 64 + 255) / 256, 256, 0, stream>>>(
                gibuf, ghbuf, x1, x2, x_h, x_l, nullptr, nullptr);
    }

    // ---------------- layer 2 (C = 256) ----------------
    for (int it = 0; it < 3; ++it) {
        const int C = D2;
        mgemm_k<true><<<dim3(4 * C / 128, MT), 256, 0, stream>>>(
            x_h, x_l, B2h + it * 1024 * C, B2l + it * 1024 * C,
            bhh2, mbuf, ghbuf, NN, 4 * C, C, C);
        gather_k<D2><<<(NN * (D2 / 4) + 255) / 256, 256, 0, stream>>>(
            mbuf, off, elist, a_h, a_l);
        mgemm_k<false><<<dim3(3 * C / 128, MT), 256, 0, stream>>>(
            a_h, a_l, wih2h, wih2l, bih2, nullptr, gibuf, NN, 3 * C, C, 0);
        if (it < 2)
            gates_k<D2, 0><<<(NN * 64 + 255) / 256, 256, 0, stream>>>(
                gibuf, ghbuf, x2, x2, x_h, x_l, nullptr, nullptr);
        else  // fused segment-max pool, no x stores
            gates_k<D2, 2><<<(NN * 64 + 255) / 256, 256, 0, stream>>>(
                gibuf, ghbuf, x2, nullptr, nullptr, nullptr, batch, pool);
    }

    fc_k<<<1, 512, 0, stream>>>(pool, fcw, fcb, out);
}

// Round 6
// 746.837 us; speedup vs baseline: 1.0309x; 1.0309x over previous
//
#include <hip/hip_runtime.h>

#define NN 10000
#define NE 320000
#define NG 64
#define D1 128
#define D2 256

typedef unsigned short u16;
typedef short v8s __attribute__((ext_vector_type(8)));
typedef float v4f __attribute__((ext_vector_type(4)));

__device__ __forceinline__ u16 f2bf(float x) {
    unsigned u = __float_as_uint(x);
    return (u16)((u + 0x7fffu + ((u >> 16) & 1u)) >> 16);
}
__device__ __forceinline__ float bf2f(u16 b) {
    return __uint_as_float(((unsigned)b) << 16);
}

// async global->LDS, 16B per lane; LDS dest = wave-uniform base + lane*16
#define GLDS16(gp, lp)                                                         \
    __builtin_amdgcn_global_load_lds(                                          \
        (__attribute__((address_space(1))) unsigned int*)(unsigned long long)(gp), \
        (__attribute__((address_space(3))) unsigned int*)(lp), 16, 0, 0)

// =====================================================================
// Split-bf16 MFMA GEMM, single-buffer LDS (round-4 proven variant —
// dbuf regressed: grid-limited 2.5 blocks/CU, 64KB LDS capped it at 2).
// D[M,N] = (Ah+Al)[M,K] @ (Bh+Bl)[N,K]^T ; 128x128 tile, 4 waves,
// 64x64/wave, 16x16x32 mfma, BK=32, 3 mfma/frag pair (drop lo*lo).
// SPLIT: cols < N0 -> Cm (stride N0, no bias); cols >= N0 -> Cg
// (stride N-N0, +bias[gc-N0]). N0 multiple of 128 (block-uniform).
// =====================================================================
template<bool SPLIT>
__global__ __launch_bounds__(256)
void mgemm_k(const u16* __restrict__ Ah, const u16* __restrict__ Al,
             const u16* __restrict__ Bh, const u16* __restrict__ Bl,
             const float* __restrict__ bias, float* __restrict__ Cm,
             float* __restrict__ Cg, int M, int N, int K, int N0) {
    __shared__ u16 lds[16384];
    const int tid = threadIdx.x;
    const int wave = tid >> 6, lane = tid & 63;
    const int wm = (wave >> 1) * 64, wn = (wave & 1) * 64;
    const int bm = blockIdx.y * 128, bn = blockIdx.x * 128;
    const int quad = lane >> 4, r16 = lane & 15;

    v4f acc[4][4] = {};

    for (int k0 = 0; k0 < K; k0 += 32) {
#pragma unroll
        for (int j = 0; j < 2; ++j) {
            int row = j * 64 + lane;
            size_t aoff = (size_t)(bm + row) * K + k0 + wave * 8;
            size_t boff = (size_t)(bn + row) * K + k0 + wave * 8;
            int s = (wave * 128 + j * 64) * 8;
            GLDS16(Ah + aoff, &lds[s]);
            GLDS16(Al + aoff, &lds[4096 + s]);
            GLDS16(Bh + boff, &lds[8192 + s]);
            GLDS16(Bl + boff, &lds[12288 + s]);
        }
        __syncthreads();

        v8s ah[4], al[4], bh[4], bl[4];
#pragma unroll
        for (int i = 0; i < 4; ++i) {
            int ra = (quad * 128 + wm + i * 16 + r16) * 8;
            int rb = (quad * 128 + wn + i * 16 + r16) * 8;
            ah[i] = *(const v8s*)&lds[ra];
            al[i] = *(const v8s*)&lds[4096 + ra];
            bh[i] = *(const v8s*)&lds[8192 + rb];
            bl[i] = *(const v8s*)&lds[12288 + rb];
        }
#pragma unroll
        for (int i = 0; i < 4; ++i)
#pragma unroll
            for (int j = 0; j < 4; ++j) {
                acc[i][j] = __builtin_amdgcn_mfma_f32_16x16x32_bf16(ah[i], bh[j], acc[i][j], 0, 0, 0);
                acc[i][j] = __builtin_amdgcn_mfma_f32_16x16x32_bf16(ah[i], bl[j], acc[i][j], 0, 0, 0);
                acc[i][j] = __builtin_amdgcn_mfma_f32_16x16x32_bf16(al[i], bh[j], acc[i][j], 0, 0, 0);
            }
        __syncthreads();
    }

    // epilogue: C/D layout col=lane&15, row=quad*4+reg
#pragma unroll
    for (int i = 0; i < 4; ++i) {
        int gr0 = bm + wm + i * 16 + quad * 4;
#pragma unroll
        for (int j = 0; j < 4; ++j) {
            int gc = bn + wn + j * 16 + r16;
            if (SPLIT && gc < N0) {  // block-uniform branch
#pragma unroll
                for (int r = 0; r < 4; ++r) {
                    int gr = gr0 + r;
                    if (gr < M) Cm[(size_t)gr * N0 + gc] = acc[i][j][r];
                }
            } else {
                int cc = SPLIT ? gc - N0 : gc;
                int ns = SPLIT ? N - N0 : N;
                float bv = bias[cc];
#pragma unroll
                for (int r = 0; r < 4; ++r) {
                    int gr = gr0 + r;
                    if (gr < M) Cg[(size_t)gr * ns + cc] = acc[i][j][r] + bv;
                }
            }
        }
    }
}

// =====================================================================
// CSR build
// =====================================================================
__global__ void count_k(const int* __restrict__ dst, int* __restrict__ cnt) {
    int e = blockIdx.x * blockDim.x + threadIdx.x;
    if (e < NE) atomicAdd(&cnt[dst[e]], 1);
}

__global__ void scan_k(const int* __restrict__ cnt, int* __restrict__ off,
                       int* __restrict__ cur) {
    __shared__ int ps[1024];
    const int tid = threadIdx.x;
    const int CH = (NN + 1023) / 1024;
    const int base = tid * CH;
    int s = 0;
    for (int i = 0; i < CH; ++i) {
        int idx = base + i;
        if (idx < NN) s += cnt[idx];
    }
    ps[tid] = s;
    __syncthreads();
    for (int d = 1; d < 1024; d <<= 1) {
        int v = (tid >= d) ? ps[tid - d] : 0;
        __syncthreads();
        ps[tid] += v;
        __syncthreads();
    }
    int run = (tid > 0) ? ps[tid - 1] : 0;
    for (int i = 0; i < CH; ++i) {
        int idx = base + i;
        if (idx <= NN) { off[idx] = run; if (idx < NN) cur[idx] = run; }
        if (idx < NN) run += cnt[idx];
    }
}

__global__ void fill_k(const int* __restrict__ src, const int* __restrict__ dst,
                       int* __restrict__ cur, int* __restrict__ elist) {
    int e = blockIdx.x * blockDim.x + threadIdx.x;
    if (e >= NE) return;
    int p = atomicAdd(&cur[dst[e]], 1);
    elist[p] = src[e];
}

// =====================================================================
// CSR gather, 4-deep software pipeline: a[n,:] = sum m[src,:], bf16 hi/lo out
// =====================================================================
template<int C>
__global__ void gather_k(const float* __restrict__ m, const int* __restrict__ off,
                         const int* __restrict__ elist,
                         u16* __restrict__ ah, u16* __restrict__ al) {
    constexpr int LPN = C / 4;
    int t = blockIdx.x * blockDim.x + threadIdx.x;
    int node = t / LPN;
    if (node >= NN) return;
    int c = (t % LPN) * 4;
    int s0 = off[node], s1 = off[node + 1];
    v4f a0 = 0.f, a1 = 0.f, a2 = 0.f, a3 = 0.f;
    int i = s0;
    for (; i + 4 <= s1; i += 4) {
        int e0 = elist[i], e1 = elist[i + 1], e2 = elist[i + 2], e3 = elist[i + 3];
        v4f v0 = *(const v4f*)(m + (size_t)e0 * C + c);
        v4f v1 = *(const v4f*)(m + (size_t)e1 * C + c);
        v4f v2 = *(const v4f*)(m + (size_t)e2 * C + c);
        v4f v3 = *(const v4f*)(m + (size_t)e3 * C + c);
        a0 += v0; a1 += v1; a2 += v2; a3 += v3;
    }
    for (; i < s1; ++i) {
        int e = elist[i];
        a0 += *(const v4f*)(m + (size_t)e * C + c);
    }
    v4f acc = (a0 + a1) + (a2 + a3);
    ushort4 h, l;
    h.x = f2bf(acc.x); l.x = f2bf(acc.x - bf2f(h.x));
    h.y = f2bf(acc.y); l.y = f2bf(acc.y - bf2f(h.y));
    h.z = f2bf(acc.z); l.z = f2bf(acc.z - bf2f(h.z));
    h.w = f2bf(acc.w); l.w = f2bf(acc.w - bf2f(h.w));
    *(ushort4*)(ah + (size_t)node * C + c) = h;
    *(ushort4*)(al + (size_t)node * C + c) = l;
}

// =====================================================================
// GRU gates, MLP-optimized: 2 quads/thread, all loads issued up front,
// h reconstructed from bf16 hi/lo (no fp32 x buffer at all).
// MODE 0: in-place update of xh/xl (stride C).
// MODE 1 (layer-1 final, C=128): relu(gru) -> xout stride 256, quads
//         j,j+16 = values; j+32,j+48 = zeros (pad 128->256).
// MODE 2 (layer-2 final, C=256): no x stores; atomicMax monotone-mapped
//         into pool[batch[n]*256 + c].
// =====================================================================
__device__ __forceinline__ v4f gru4(v4f ir, v4f iz, v4f inn, v4f hr, v4f hz,
                                    v4f hn, v4f h) {
    v4f o;
#pragma unroll
    for (int k = 0; k < 4; ++k) {
        float r = 1.f / (1.f + expf(-(ir[k] + hr[k])));
        float z = 1.f / (1.f + expf(-(iz[k] + hz[k])));
        float nn_ = tanhf(inn[k] + r * hn[k]);
        o[k] = (1.f - z) * nn_ + z * h[k];
    }
    return o;
}

template<int C, int MODE>
__global__ void gates_k(const float* __restrict__ gi, const float* __restrict__ gh,
                        const u16* __restrict__ xh_in, const u16* __restrict__ xl_in,
                        u16* __restrict__ xh_out, u16* __restrict__ xl_out,
                        const int* __restrict__ batch, unsigned* __restrict__ pool) {
    constexpr int Q = C / 4;   // quads per node
    constexpr int H = Q / 2;   // threads per node (2 quads each)
    int t = blockIdx.x * blockDim.x + threadIdx.x;
    if (t >= NN * H) return;
    int n = t / H, j = t - n * H;

    const v4f* gp = (const v4f*)(gi + (size_t)n * 3 * C);
    const v4f* hp = (const v4f*)(gh + (size_t)n * 3 * C);
    // issue all 18 loads before any use (MLP)
    v4f ir0 = gp[j],         ir1 = gp[j + H];
    v4f iz0 = gp[Q + j],     iz1 = gp[Q + j + H];
    v4f in0 = gp[2 * Q + j], in1 = gp[2 * Q + j + H];
    v4f hr0 = hp[j],         hr1 = hp[j + H];
    v4f hz0 = hp[Q + j],     hz1 = hp[Q + j + H];
    v4f hn0 = hp[2 * Q + j], hn1 = hp[2 * Q + j + H];
    ushort4 h0h = *(const ushort4*)(xh_in + (size_t)n * C + j * 4);
    ushort4 h0l = *(const ushort4*)(xl_in + (size_t)n * C + j * 4);
    ushort4 h1h = *(const ushort4*)(xh_in + (size_t)n * C + (j + H) * 4);
    ushort4 h1l = *(const ushort4*)(xl_in + (size_t)n * C + (j + H) * 4);

    v4f h0, h1;
    h0[0] = bf2f(h0h.x) + bf2f(h0l.x); h0[1] = bf2f(h0h.y) + bf2f(h0l.y);
    h0[2] = bf2f(h0h.z) + bf2f(h0l.z); h0[3] = bf2f(h0h.w) + bf2f(h0l.w);
    h1[0] = bf2f(h1h.x) + bf2f(h1l.x); h1[1] = bf2f(h1h.y) + bf2f(h1l.y);
    h1[2] = bf2f(h1h.z) + bf2f(h1l.z); h1[3] = bf2f(h1h.w) + bf2f(h1l.w);

    v4f o0 = gru4(ir0, iz0, in0, hr0, hz0, hn0, h0);
    v4f o1 = gru4(ir1, iz1, in1, hr1, hz1, hn1, h1);

    if (MODE == 2) {
        int pb = batch[n] * 256;
#pragma unroll
        for (int k = 0; k < 4; ++k) {
            unsigned b0 = __float_as_uint(o0[k]);
            unsigned u0 = (b0 & 0x80000000u) ? ~b0 : (b0 | 0x80000000u);
            atomicMax(&pool[pb + j * 4 + k], u0);
            unsigned b1 = __float_as_uint(o1[k]);
            unsigned u1 = (b1 & 0x80000000u) ? ~b1 : (b1 | 0x80000000u);
            atomicMax(&pool[pb + (j + H) * 4 + k], u1);
        }
        return;
    }

    if (MODE == 1) {
#pragma unroll
        for (int k = 0; k < 4; ++k) {
            o0[k] = fmaxf(o0[k], 0.f);
            o1[k] = fmaxf(o1[k], 0.f);
        }
    }
    constexpr int OS = (MODE == 1) ? 256 : C;  // output row stride
    ushort4 s0h, s0l, s1h, s1l;
    s0h.x = f2bf(o0[0]); s0l.x = f2bf(o0[0] - bf2f(s0h.x));
    s0h.y = f2bf(o0[1]); s0l.y = f2bf(o0[1] - bf2f(s0h.y));
    s0h.z = f2bf(o0[2]); s0l.z = f2bf(o0[2] - bf2f(s0h.z));
    s0h.w = f2bf(o0[3]); s0l.w = f2bf(o0[3] - bf2f(s0h.w));
    s1h.x = f2bf(o1[0]); s1l.x = f2bf(o1[0] - bf2f(s1h.x));
    s1h.y = f2bf(o1[1]); s1l.y = f2bf(o1[1] - bf2f(s1h.y));
    s1h.z = f2bf(o1[2]); s1l.z = f2bf(o1[2] - bf2f(s1h.z));
    s1h.w = f2bf(o1[3]); s1l.w = f2bf(o1[3] - bf2f(s1h.w));
    *(ushort4*)(xh_out + (size_t)n * OS + j * 4) = s0h;
    *(ushort4*)(xl_out + (size_t)n * OS + j * 4) = s0l;
    *(ushort4*)(xh_out + (size_t)n * OS + (j + H) * 4) = s1h;
    *(ushort4*)(xl_out + (size_t)n * OS + (j + H) * 4) = s1l;
    if (MODE == 1) {  // pad cols 128..255 with zeros
        ushort4 z4 = {0, 0, 0, 0};
        *(ushort4*)(xh_out + (size_t)n * 256 + (j + 32) * 4) = z4;
        *(ushort4*)(xl_out + (size_t)n * 256 + (j + 32) * 4) = z4;
        *(ushort4*)(xh_out + (size_t)n * 256 + (j + 48) * 4) = z4;
        *(ushort4*)(xl_out + (size_t)n * 256 + (j + 48) * 4) = z4;
    }
}

// =====================================================================
// prep_k: all weight conversions + x-init (bf16 hi/lo only) in one launch.
// B1cat[it] = [512,128]:  rows 0..127 = w1[it]^T, rows 128..511 = whh1
// B2cat[it] = [1024,256]: rows 0..255 = w2[it]^T, rows 256..1023 = whh2
// =====================================================================
__global__ void prep_k(const float* __restrict__ w1, const float* __restrict__ whh1,
                       const float* __restrict__ wih1, const float* __restrict__ w2,
                       const float* __restrict__ whh2, const float* __restrict__ wih2,
                       const float* __restrict__ xin,
                       u16* __restrict__ B1h, u16* __restrict__ B1l,
                       u16* __restrict__ B2h, u16* __restrict__ B2l,
                       u16* __restrict__ wih1h, u16* __restrict__ wih1l,
                       u16* __restrict__ wih2h, u16* __restrict__ wih2l,
                       u16* __restrict__ xh, u16* __restrict__ xl) {
    const int n1 = 3 * D1 * D1, n2 = 3 * D2 * D2;
    int t = blockIdx.x * blockDim.x + threadIdx.x;
    if (t < n1) {  // w1 transpose
        int l = t / (D1 * D1), rem = t - l * D1 * D1;
        int k = rem / D1, n = rem - k * D1;
        float v = w1[t]; u16 h = f2bf(v), lo = f2bf(v - bf2f(h));
        int o = (l * 512 + n) * D1 + k;
        B1h[o] = h; B1l[o] = lo; return;
    }
    t -= n1;
    if (t < n1) {  // whh1 replicate x3
        float v = whh1[t]; u16 h = f2bf(v), lo = f2bf(v - bf2f(h));
        int r = t / D1, k = t - r * D1;
#pragma unroll
        for (int l = 0; l < 3; ++l) {
            int o = (l * 512 + 128 + r) * D1 + k;
            B1h[o] = h; B1l[o] = lo;
        }
        return;
    }
    t -= n1;
    if (t < n2) {  // w2 transpose
        int l = t / (D2 * D2), rem = t - l * D2 * D2;
        int k = rem / D2, n = rem - k * D2;
        float v = w2[t]; u16 h = f2bf(v), lo = f2bf(v - bf2f(h));
        int o = (l * 1024 + n) * D2 + k;
        B2h[o] = h; B2l[o] = lo; return;
    }
    t -= n2;
    if (t < n2) {  // whh2 replicate x3
        float v = whh2[t]; u16 h = f2bf(v), lo = f2bf(v - bf2f(h));
        int r = t / D2, k = t - r * D2;
#pragma unroll
        for (int l = 0; l < 3; ++l) {
            int o = (l * 1024 + 256 + r) * D2 + k;
            B2h[o] = h; B2l[o] = lo;
        }
        return;
    }
    t -= n2;
    if (t < n1) { float v = wih1[t]; u16 h = f2bf(v); wih1h[t] = h; wih1l[t] = f2bf(v - bf2f(h)); return; }
    t -= n1;
    if (t < n2) { float v = wih2[t]; u16 h = f2bf(v); wih2h[t] = h; wih2l[t] = f2bf(v - bf2f(h)); return; }
    t -= n2;
    if (t < NN * D1) {  // x init (hi/lo only)
        float v = xin[t];
        u16 h = f2bf(v);
        xh[t] = h;
        xl[t] = f2bf(v - bf2f(h));
    }
}

__global__ void pool_init_k(unsigned* __restrict__ pool) {
    int t = blockIdx.x * blockDim.x + threadIdx.x;
    if (t < NG * D2) pool[t] = 0x007FFFFFu;  // mapped(-inf)
}

__global__ void fc_k(const unsigned* __restrict__ pool, const float* __restrict__ w,
                     const float* __restrict__ b, float* __restrict__ out) {
    int t = blockIdx.x * blockDim.x + threadIdx.x;
    if (t >= NG * 6) return;
    int g = t / 6, o = t - g * 6;
    float s = b[o];
    for (int c = 0; c < D2; ++c) {
        unsigned u = pool[g * D2 + c];
        unsigned bits = (u & 0x80000000u) ? (u ^ 0x80000000u) : ~u;
        s += __uint_as_float(bits) * w[o * D2 + c];
    }
    out[t] = s;
}

// =======================================================================
extern "C" void kernel_launch(void* const* d_in, const int* in_sizes, int n_in,
                              void* d_out, int out_size, void* d_ws, size_t ws_size,
                              hipStream_t stream) {
    const float* x_in = (const float*)d_in[0];
    const int* ei = (const int*)d_in[1];
    const int* src = ei;
    const int* dst = ei + NE;
    const int* batch = (const int*)d_in[2];
    const float* w1   = (const float*)d_in[3];
    const float* wih1 = (const float*)d_in[4];
    const float* whh1 = (const float*)d_in[5];
    const float* bih1 = (const float*)d_in[6];
    const float* bhh1 = (const float*)d_in[7];
    const float* w2   = (const float*)d_in[8];
    const float* wih2 = (const float*)d_in[9];
    const float* whh2 = (const float*)d_in[10];
    const float* bih2 = (const float*)d_in[11];
    const float* bhh2 = (const float*)d_in[12];
    const float* fcw  = (const float*)d_in[13];
    const float* fcb  = (const float*)d_in[14];
    float* out = (float*)d_out;

    // ---- workspace layout ----
    // mbuf aliases gibuf: fused GEMM writes m -> gather reads m, writes a_hl
    // -> gi GEMM overwrites gibuf (m dead, reads a_hl). gh separate.
    float* ws = (float*)d_ws;
    float* gibuf = ws;                        // [NN,768] fp32
    float* mbuf  = gibuf;                     // alias [NN,<=256] fp32
    float* ghbuf = gibuf + NN * 768;          // [NN,768] fp32
    u16* a_h = (u16*)(ghbuf + NN * 768);      // [NN,256] bf16
    u16* a_l = a_h + NN * 256;
    u16* xA_h = a_l + NN * 256;               // [NN,128] layer-1 x hi/lo
    u16* xA_l = xA_h + NN * 128;
    u16* xB_h = xA_l + NN * 128;              // [NN,256] layer-2 x hi/lo
    u16* xB_l = xB_h + NN * 256;
    u16* B1h = xB_l + NN * 256;               // [3][512][128]
    u16* B1l = B1h + 3 * 512 * D1;
    u16* B2h = B1l + 3 * 512 * D1;            // [3][1024][256]
    u16* B2l = B2h + 3 * 1024 * D2;
    u16* wih1h = B2l + 3 * 1024 * D2;         // [384,128]
    u16* wih1l = wih1h + 3 * D1 * D1;
    u16* wih2h = wih1l + 3 * D1 * D1;         // [768,256]
    u16* wih2l = wih2h + 3 * D2 * D2;
    int* cnt   = (int*)(wih2l + 3 * D2 * D2);
    int* off   = cnt + NN;
    int* cur   = off + NN + 1;
    int* elist = cur + NN;
    unsigned* pool = (unsigned*)(elist + NE);

    // ---- CSR build + prep + pool init ----
    hipMemsetAsync(cnt, 0, NN * sizeof(int), stream);
    count_k<<<(NE + 255) / 256, 256, 0, stream>>>(dst, cnt);
    scan_k<<<1, 1024, 0, stream>>>(cnt, off, cur);
    fill_k<<<(NE + 255) / 256, 256, 0, stream>>>(src, dst, cur, elist);
    {
        int total = 3 * (3 * D1 * D1) + 3 * (3 * D2 * D2) + NN * D1;
        prep_k<<<(total + 255) / 256, 256, 0, stream>>>(
            w1, whh1, wih1, w2, whh2, wih2, x_in,
            B1h, B1l, B2h, B2l, wih1h, wih1l, wih2h, wih2l, xA_h, xA_l);
    }
    pool_init_k<<<(NG * D2 + 255) / 256, 256, 0, stream>>>(pool);

    const int MT = (NN + 127) / 128;  // 79

    // ---------------- layer 1 (C = 128) ----------------
    for (int it = 0; it < 3; ++it) {
        const int C = D1;
        mgemm_k<true><<<dim3(4 * C / 128, MT), 256, 0, stream>>>(
            xA_h, xA_l, B1h + it * 512 * C, B1l + it * 512 * C,
            bhh1, mbuf, ghbuf, NN, 4 * C, C, C);
        gather_k<D1><<<(NN * (D1 / 4) + 255) / 256, 256, 0, stream>>>(
            mbuf, off, elist, a_h, a_l);
        mgemm_k<false><<<dim3(3 * C / 128, MT), 256, 0, stream>>>(
            a_h, a_l, wih1h, wih1l, bih1, nullptr, gibuf, NN, 3 * C, C, 0);
        if (it < 2)
            gates_k<D1, 0><<<(NN * 16 + 255) / 256, 256, 0, stream>>>(
                gibuf, ghbuf, xA_h, xA_l, xA_h, xA_l, nullptr, nullptr);
        else  // fused relu + pad -> xB (stride 256)
            gates_k<D1, 1><<<(NN * 16 + 255) / 256, 256, 0, stream>>>(
                gibuf, ghbuf, xA_h, xA_l, xB_h, xB_l, nullptr, nullptr);
    }

    // ---------------- layer 2 (C = 256) ----------------
    for (int it = 0; it < 3; ++it) {
        const int C = D2;
        mgemm_k<true><<<dim3(4 * C / 128, MT), 256, 0, stream>>>(
            xB_h, xB_l, B2h + it * 1024 * C, B2l + it * 1024 * C,
            bhh2, mbuf, ghbuf, NN, 4 * C, C, C);
        gather_k<D2><<<(NN * (D2 / 4) + 255) / 256, 256, 0, stream>>>(
            mbuf, off, elist, a_h, a_l);
        mgemm_k<false><<<dim3(3 * C / 128, MT), 256, 0, stream>>>(
            a_h, a_l, wih2h, wih2l, bih2, nullptr, gibuf, NN, 3 * C, C, 0);
        if (it < 2)
            gates_k<D2, 0><<<(NN * 32 + 255) / 256, 256, 0, stream>>>(
                gibuf, ghbuf, xB_h, xB_l, xB_h, xB_l, nullptr, nullptr);
        else  // fused segment-max pool, no x stores
            gates_k<D2, 2><<<(NN * 32 + 255) / 256, 256, 0, stream>>>(
                gibuf, ghbuf, xB_h, xB_l, nullptr, nullptr, batch, pool);
    }

    fc_k<<<1, 512, 0, stream>>>(pool, fcw, fcb, out);
}

// Round 7
// 719.948 us; speedup vs baseline: 1.0694x; 1.0373x over previous
//
#include <hip/hip_runtime.h>

#define NN 10000
#define NNP 10112  // 79*128 padded rows (slack reads OK)
#define NE 320000
#define NG 64
#define D1 128
#define D2 256

typedef unsigned short u16;
typedef short v8s __attribute__((ext_vector_type(8)));
typedef float v4f __attribute__((ext_vector_type(4)));

__device__ __forceinline__ u16 f2bf(float x) {
    unsigned u = __float_as_uint(x);
    return (u16)((u + 0x7fffu + ((u >> 16) & 1u)) >> 16);
}
__device__ __forceinline__ float bf2f(u16 b) {
    return __uint_as_float(((unsigned)b) << 16);
}
__device__ __forceinline__ float sigm(float x) { return 1.f / (1.f + expf(-x)); }

// async global->LDS, 16B per lane; LDS dest = wave-uniform base + lane*16
#define GLDS16(gp, lp)                                                         \
    __builtin_amdgcn_global_load_lds(                                          \
        (__attribute__((address_space(1))) unsigned int*)(unsigned long long)(gp), \
        (__attribute__((address_space(3))) unsigned int*)(lp), 16, 0, 0)

// =====================================================================
// Plain split-bf16 MFMA GEMM (m = x @ w): C[M,N] = (Ah+Al) @ (Bh+Bl)^T
// 128x128 tile, 4 waves, 64x64/wave, 16x16x32 mfma, BK=32, single-buffer
// (round-4 proven: dbuf regressed on this grid-limited shape).
// =====================================================================
__global__ __launch_bounds__(256)
void mgemm_k(const u16* __restrict__ Ah, const u16* __restrict__ Al,
             const u16* __restrict__ Bh, const u16* __restrict__ Bl,
             float* __restrict__ C, int M, int N, int K) {
    __shared__ u16 lds[16384];
    const int tid = threadIdx.x;
    const int wave = tid >> 6, lane = tid & 63;
    const int wm = (wave >> 1) * 64, wn = (wave & 1) * 64;
    const int bm = blockIdx.y * 128, bn = blockIdx.x * 128;
    const int quad = lane >> 4, r16 = lane & 15;

    v4f acc[4][4] = {};
    for (int k0 = 0; k0 < K; k0 += 32) {
#pragma unroll
        for (int j = 0; j < 2; ++j) {
            int row = j * 64 + lane;
            size_t aoff = (size_t)(bm + row) * K + k0 + wave * 8;
            size_t boff = (size_t)(bn + row) * K + k0 + wave * 8;
            int s = (wave * 128 + j * 64) * 8;
            GLDS16(Ah + aoff, &lds[s]);
            GLDS16(Al + aoff, &lds[4096 + s]);
            GLDS16(Bh + boff, &lds[8192 + s]);
            GLDS16(Bl + boff, &lds[12288 + s]);
        }
        __syncthreads();
        v8s ah[4], al[4], bh[4], bl[4];
#pragma unroll
        for (int i = 0; i < 4; ++i) {
            int ra = (quad * 128 + wm + i * 16 + r16) * 8;
            int rb = (quad * 128 + wn + i * 16 + r16) * 8;
            ah[i] = *(const v8s*)&lds[ra];
            al[i] = *(const v8s*)&lds[4096 + ra];
            bh[i] = *(const v8s*)&lds[8192 + rb];
            bl[i] = *(const v8s*)&lds[12288 + rb];
        }
#pragma unroll
        for (int i = 0; i < 4; ++i)
#pragma unroll
            for (int j = 0; j < 4; ++j) {
                acc[i][j] = __builtin_amdgcn_mfma_f32_16x16x32_bf16(ah[i], bh[j], acc[i][j], 0, 0, 0);
                acc[i][j] = __builtin_amdgcn_mfma_f32_16x16x32_bf16(ah[i], bl[j], acc[i][j], 0, 0, 0);
                acc[i][j] = __builtin_amdgcn_mfma_f32_16x16x32_bf16(al[i], bh[j], acc[i][j], 0, 0, 0);
            }
        __syncthreads();
    }
#pragma unroll
    for (int i = 0; i < 4; ++i) {
        int gr0 = bm + wm + i * 16 + quad * 4;
#pragma unroll
        for (int j = 0; j < 4; ++j) {
            int gc = bn + wn + j * 16 + r16;
#pragma unroll
            for (int r = 0; r < 4; ++r) {
                int gr = gr0 + r;
                if (gr < M) C[(size_t)gr * N + gc] = acc[i][j][r];
            }
        }
    }
}

// =====================================================================
// Fused GRU GEMM. Weight rows permuted so col j' = chunk*48 + gate*16 + m
// encodes (channel c = chunk*16+m, gate). Block tile 128 rows x 96 cols
// (= 32 channels x 3 gates); wave tile 64x48 (16 channels). Accumulator
// j-index = gate; the 3 gates of channel c live in the SAME lane.
// Phase 0: acc_i = a @ wih'^T ; Phase 1: acc_h = x @ whh'^T.
// Epilogue: full GRU per lane; writes new x bf16 hi/lo (double-buffered
// x: reads x_cur everywhere, writes x_nxt only).
// MODE 0: store stride OS. MODE 1: relu, store stride 256 (layer1->2).
// MODE 2: no store; atomicMax monotone-mapped into pool.
// =====================================================================
template<int MODE, int OS>
__global__ __launch_bounds__(256)
void gru_k(const u16* __restrict__ Aa_h, const u16* __restrict__ Aa_l,
           const u16* __restrict__ Ax_h, const u16* __restrict__ Ax_l,
           const u16* __restrict__ Bi_h, const u16* __restrict__ Bi_l,
           const u16* __restrict__ Bh_h, const u16* __restrict__ Bh_l,
           const float* __restrict__ bih, const float* __restrict__ bhh,
           u16* __restrict__ xh_out, u16* __restrict__ xl_out,
           const int* __restrict__ batch, unsigned* __restrict__ pool,
           int M, int C) {
    __shared__ u16 lds[14336];  // A hi 0, A lo 4096, B hi 8192, B lo 11264
    const int tid = threadIdx.x;
    const int wave = tid >> 6, lane = tid & 63;
    const int wm = (wave >> 1) * 64;   // row half
    const int wn = (wave & 1) * 48;    // col half (16 channels x 3 gates)
    const int bm = blockIdx.y * 128;
    const int bcol = blockIdx.x * 96;  // permuted B-row base
    const int quad = lane >> 4, r16 = lane & 15;

    v4f acc_i[4][3] = {}, acc_h[4][3] = {};

    auto kloop = [&](const u16* APh, const u16* APl, const u16* BPh,
                     const u16* BPl, v4f (&acc)[4][3]) {
        for (int k0 = 0; k0 < C; k0 += 32) {
            // stage A: 128 rows, wave covers kh=wave
#pragma unroll
            for (int j = 0; j < 2; ++j) {
                int row = j * 64 + lane;
                size_t g = (size_t)(bm + row) * C + k0 + wave * 8;
                int s = (wave * 128 + row) * 8;
                GLDS16(APh + g, &lds[s]);
                GLDS16(APl + g, &lds[4096 + s]);
            }
            // stage B: 96 rows
            {
                int row = lane;
                size_t g = (size_t)(bcol + row) * C + k0 + wave * 8;
                int s = (wave * 96 + row) * 8;
                GLDS16(BPh + g, &lds[8192 + s]);
                GLDS16(BPl + g, &lds[11264 + s]);
                if (lane < 32) {
                    row = 64 + lane;
                    g = (size_t)(bcol + row) * C + k0 + wave * 8;
                    s = (wave * 96 + row) * 8;
                    GLDS16(BPh + g, &lds[8192 + s]);
                    GLDS16(BPl + g, &lds[11264 + s]);
                }
            }
            __syncthreads();
            v8s fah[4], fal[4], fbh[3], fbl[3];
#pragma unroll
            for (int i = 0; i < 4; ++i) {
                int ra = (quad * 128 + wm + i * 16 + r16) * 8;
                fah[i] = *(const v8s*)&lds[ra];
                fal[i] = *(const v8s*)&lds[4096 + ra];
            }
#pragma unroll
            for (int g = 0; g < 3; ++g) {
                int rb = (quad * 96 + wn + g * 16 + r16) * 8;
                fbh[g] = *(const v8s*)&lds[8192 + rb];
                fbl[g] = *(const v8s*)&lds[11264 + rb];
            }
#pragma unroll
            for (int i = 0; i < 4; ++i)
#pragma unroll
                for (int g = 0; g < 3; ++g) {
                    acc[i][g] = __builtin_amdgcn_mfma_f32_16x16x32_bf16(fah[i], fbh[g], acc[i][g], 0, 0, 0);
                    acc[i][g] = __builtin_amdgcn_mfma_f32_16x16x32_bf16(fah[i], fbl[g], acc[i][g], 0, 0, 0);
                    acc[i][g] = __builtin_amdgcn_mfma_f32_16x16x32_bf16(fal[i], fbh[g], acc[i][g], 0, 0, 0);
                }
            __syncthreads();
        }
    };
    kloop(Aa_h, Aa_l, Bi_h, Bi_l, acc_i);
    kloop(Ax_h, Ax_l, Bh_h, Bh_l, acc_h);

    // epilogue: C/D layout col=lane&15 (-> channel), row=quad*4+reg
    const int c = (blockIdx.x * 2 + (wn ? 1 : 0)) * 16 + r16;  // channel
    const float bir = bih[c],         bhr = bhh[c];
    const float biz = bih[C + c],     bhz = bhh[C + c];
    const float bin = bih[2 * C + c], bhn = bhh[2 * C + c];
#pragma unroll
    for (int i = 0; i < 4; ++i) {
        int R0 = bm + wm + i * 16 + quad * 4;
#pragma unroll
        for (int r = 0; r < 4; ++r) {
            int R = R0 + r;
            if (R >= M) continue;
            float rr = sigm(acc_i[i][0][r] + bir + acc_h[i][0][r] + bhr);
            float zz = sigm(acc_i[i][1][r] + biz + acc_h[i][1][r] + bhz);
            float nn_ = tanhf(acc_i[i][2][r] + bin + rr * (acc_h[i][2][r] + bhn));
            float h = bf2f(Ax_h[(size_t)R * C + c]) + bf2f(Ax_l[(size_t)R * C + c]);
            float o = (1.f - zz) * nn_ + zz * h;
            if (MODE == 2) {
                unsigned b = __float_as_uint(o);
                unsigned u = (b & 0x80000000u) ? ~b : (b | 0x80000000u);
                atomicMax(&pool[batch[R] * 256 + c], u);
            } else {
                if (MODE == 1) o = fmaxf(o, 0.f);
                u16 hh = f2bf(o);
                xh_out[(size_t)R * OS + c] = hh;
                xl_out[(size_t)R * OS + c] = f2bf(o - bf2f(hh));
            }
        }
    }
}

// =====================================================================
// CSR build
// =====================================================================
__global__ void count_k(const int* __restrict__ dst, int* __restrict__ cnt) {
    int e = blockIdx.x * blockDim.x + threadIdx.x;
    if (e < NE) atomicAdd(&cnt[dst[e]], 1);
}

__global__ void scan_k(const int* __restrict__ cnt, int* __restrict__ off,
                       int* __restrict__ cur) {
    __shared__ int ps[1024];
    const int tid = threadIdx.x;
    const int CH = (NN + 1023) / 1024;
    const int base = tid * CH;
    int s = 0;
    for (int i = 0; i < CH; ++i) {
        int idx = base + i;
        if (idx < NN) s += cnt[idx];
    }
    ps[tid] = s;
    __syncthreads();
    for (int d = 1; d < 1024; d <<= 1) {
        int v = (tid >= d) ? ps[tid - d] : 0;
        __syncthreads();
        ps[tid] += v;
        __syncthreads();
    }
    int run = (tid > 0) ? ps[tid - 1] : 0;
    for (int i = 0; i < CH; ++i) {
        int idx = base + i;
        if (idx <= NN) { off[idx] = run; if (idx < NN) cur[idx] = run; }
        if (idx < NN) run += cnt[idx];
    }
}

__global__ void fill_k(const int* __restrict__ src, const int* __restrict__ dst,
                       int* __restrict__ cur, int* __restrict__ elist) {
    int e = blockIdx.x * blockDim.x + threadIdx.x;
    if (e >= NE) return;
    int p = atomicAdd(&cur[dst[e]], 1);
    elist[p] = src[e];
}

// =====================================================================
// CSR gather, 4-deep pipeline: a[n,:] = sum m[src,:], bf16 hi/lo out
// =====================================================================
template<int C>
__global__ void gather_k(const float* __restrict__ m, const int* __restrict__ off,
                         const int* __restrict__ elist,
                         u16* __restrict__ ah, u16* __restrict__ al) {
    constexpr int LPN = C / 4;
    int t = blockIdx.x * blockDim.x + threadIdx.x;
    int node = t / LPN;
    if (node >= NN) return;
    int c = (t % LPN) * 4;
    int s0 = off[node], s1 = off[node + 1];
    v4f a0 = 0.f, a1 = 0.f, a2 = 0.f, a3 = 0.f;
    int i = s0;
    for (; i + 4 <= s1; i += 4) {
        int e0 = elist[i], e1 = elist[i + 1], e2 = elist[i + 2], e3 = elist[i + 3];
        v4f v0 = *(const v4f*)(m + (size_t)e0 * C + c);
        v4f v1 = *(const v4f*)(m + (size_t)e1 * C + c);
        v4f v2 = *(const v4f*)(m + (size_t)e2 * C + c);
        v4f v3 = *(const v4f*)(m + (size_t)e3 * C + c);
        a0 += v0; a1 += v1; a2 += v2; a3 += v3;
    }
    for (; i < s1; ++i) {
        int e = elist[i];
        a0 += *(const v4f*)(m + (size_t)e * C + c);
    }
    v4f acc = (a0 + a1) + (a2 + a3);
    ushort4 h, l;
    h.x = f2bf(acc.x); l.x = f2bf(acc.x - bf2f(h.x));
    h.y = f2bf(acc.y); l.y = f2bf(acc.y - bf2f(h.y));
    h.z = f2bf(acc.z); l.z = f2bf(acc.z - bf2f(h.z));
    h.w = f2bf(acc.w); l.w = f2bf(acc.w - bf2f(h.w));
    *(ushort4*)(ah + (size_t)node * C + c) = h;
    *(ushort4*)(al + (size_t)node * C + c) = l;
}

// =====================================================================
// prep_k: weight transforms + x init, one launch.
// w1t/w2t: transposed to [N,K] for the m GEMM.
// wih/whh: row-permute j = g*C + c  ->  j' = (c/16)*48 + g*16 + (c%16).
// =====================================================================
__global__ void prep_k(const float* __restrict__ w1, const float* __restrict__ w2,
                       const float* __restrict__ wih1, const float* __restrict__ whh1,
                       const float* __restrict__ wih2, const float* __restrict__ whh2,
                       const float* __restrict__ xin,
                       u16* __restrict__ w1t_h, u16* __restrict__ w1t_l,
                       u16* __restrict__ w2t_h, u16* __restrict__ w2t_l,
                       u16* __restrict__ wi1_h, u16* __restrict__ wi1_l,
                       u16* __restrict__ wh1_h, u16* __restrict__ wh1_l,
                       u16* __restrict__ wi2_h, u16* __restrict__ wi2_l,
                       u16* __restrict__ wh2_h, u16* __restrict__ wh2_l,
                       u16* __restrict__ xh, u16* __restrict__ xl) {
    const int n1 = 3 * D1 * D1, n2 = 3 * D2 * D2;
    int t = blockIdx.x * blockDim.x + threadIdx.x;
    if (t < n1) {  // w1 transpose [L][K][N] -> [L][N][K]
        int l = t / (D1 * D1), rem = t - l * (D1 * D1);
        int k = rem / D1, n = rem - k * D1;
        float v = w1[t]; u16 h = f2bf(v);
        int o = (l * D1 + n) * D1 + k;
        w1t_h[o] = h; w1t_l[o] = f2bf(v - bf2f(h)); return;
    }
    t -= n1;
    if (t < n2) {  // w2 transpose
        int l = t / (D2 * D2), rem = t - l * (D2 * D2);
        int k = rem / D2, n = rem - k * D2;
        float v = w2[t]; u16 h = f2bf(v);
        int o = (l * D2 + n) * D2 + k;
        w2t_h[o] = h; w2t_l[o] = f2bf(v - bf2f(h)); return;
    }
    t -= n2;
    if (t < 2 * n1) {  // wih1 / whh1 permute (C=128)
        const float* srcw = (t < n1) ? wih1 : whh1;
        u16* dh = (t < n1) ? wi1_h : wh1_h;
        u16* dl = (t < n1) ? wi1_l : wh1_l;
        int tt = (t < n1) ? t : t - n1;
        int j = tt / D1, k = tt - j * D1;
        int g = j / D1 ? j / D1 : 0;  // careful: j in [0,384)
        g = j >> 7;                   // /128
        int c = j & 127;
        int jp = (c >> 4) * 48 + g * 16 + (c & 15);
        float v = srcw[tt]; u16 h = f2bf(v);
        dh[jp * D1 + k] = h; dl[jp * D1 + k] = f2bf(v - bf2f(h)); return;
    }
    t -= 2 * n1;
    if (t < 2 * n2) {  // wih2 / whh2 permute (C=256)
        const float* srcw = (t < n2) ? wih2 : whh2;
        u16* dh = (t < n2) ? wi2_h : wh2_h;
        u16* dl = (t < n2) ? wi2_l : wh2_l;
        int tt = (t < n2) ? t : t - n2;
        int j = tt / D2, k = tt - j * D2;
        int g = j >> 8;               // /256
        int c = j & 255;
        int jp = (c >> 4) * 48 + g * 16 + (c & 15);
        float v = srcw[tt]; u16 h = f2bf(v);
        dh[jp * D2 + k] = h; dl[jp * D2 + k] = f2bf(v - bf2f(h)); return;
    }
    t -= 2 * n2;
    if (t < NN * D1) {  // x init (bf16 hi/lo only)
        float v = xin[t];
        u16 h = f2bf(v);
        xh[t] = h;
        xl[t] = f2bf(v - bf2f(h));
    }
}

// zero the pad region (cols 128..255) of the layer-2 transition x buffer
__global__ void pad_k(u16* __restrict__ xh, u16* __restrict__ xl) {
    int t = blockIdx.x * blockDim.x + threadIdx.x;
    if (t >= NN * 128) return;
    int n = t >> 7, c = 128 + (t & 127);
    xh[n * 256 + c] = 0;
    xl[n * 256 + c] = 0;
}

__global__ void pool_init_k(unsigned* __restrict__ pool) {
    int t = blockIdx.x * blockDim.x + threadIdx.x;
    if (t < NG * D2) pool[t] = 0x007FFFFFu;  // mapped(-inf)
}

__global__ void fc_k(const unsigned* __restrict__ pool, const float* __restrict__ w,
                     const float* __restrict__ b, float* __restrict__ out) {
    int t = blockIdx.x * blockDim.x + threadIdx.x;
    if (t >= NG * 6) return;
    int g = t / 6, o = t - g * 6;
    float s = b[o];
    for (int c = 0; c < D2; ++c) {
        unsigned u = pool[g * D2 + c];
        unsigned bits = (u & 0x80000000u) ? (u ^ 0x80000000u) : ~u;
        s += __uint_as_float(bits) * w[o * D2 + c];
    }
    out[t] = s;
}

// =======================================================================
extern "C" void kernel_launch(void* const* d_in, const int* in_sizes, int n_in,
                              void* d_out, int out_size, void* d_ws, size_t ws_size,
                              hipStream_t stream) {
    const float* x_in = (const float*)d_in[0];
    const int* ei = (const int*)d_in[1];
    const int* src = ei;
    const int* dst = ei + NE;
    const int* batch = (const int*)d_in[2];
    const float* w1   = (const float*)d_in[3];
    const float* wih1 = (const float*)d_in[4];
    const float* whh1 = (const float*)d_in[5];
    const float* bih1 = (const float*)d_in[6];
    const float* bhh1 = (const float*)d_in[7];
    const float* w2   = (const float*)d_in[8];
    const float* wih2 = (const float*)d_in[9];
    const float* whh2 = (const float*)d_in[10];
    const float* bih2 = (const float*)d_in[11];
    const float* bhh2 = (const float*)d_in[12];
    const float* fcw  = (const float*)d_in[13];
    const float* fcb  = (const float*)d_in[14];
    float* out = (float*)d_out;

    // ---- workspace (~30 MB; x double-buffered: gru reads x_cur, writes x_nxt)
    float* ws = (float*)d_ws;
    float* mbuf = ws;                          // [NNP,256] fp32
    u16* a_h = (u16*)(mbuf + NNP * 256);       // [NNP,256]
    u16* a_l = a_h + NNP * 256;
    u16* xA_h[2], *xA_l[2], *xB_h[2], *xB_l[2];
    xA_h[0] = a_l + NNP * 256;                 // [NNP,128] x2
    xA_l[0] = xA_h[0] + NNP * 128;
    xA_h[1] = xA_l[0] + NNP * 128;
    xA_l[1] = xA_h[1] + NNP * 128;
    xB_h[0] = xA_l[1] + NNP * 128;             // [NNP,256] x2
    xB_l[0] = xB_h[0] + NNP * 256;
    xB_h[1] = xB_l[0] + NNP * 256;
    xB_l[1] = xB_h[1] + NNP * 256;
    u16* w1t_h = xB_l[1] + NNP * 256;          // [3][128][128]
    u16* w1t_l = w1t_h + 3 * D1 * D1;
    u16* w2t_h = w1t_l + 3 * D1 * D1;          // [3][256][256]
    u16* w2t_l = w2t_h + 3 * D2 * D2;
    u16* wi1_h = w2t_l + 3 * D2 * D2;          // permuted [384,128]
    u16* wi1_l = wi1_h + 3 * D1 * D1;
    u16* wh1_h = wi1_l + 3 * D1 * D1;
    u16* wh1_l = wh1_h + 3 * D1 * D1;
    u16* wi2_h = wh1_l + 3 * D1 * D1;          // permuted [768,256]
    u16* wi2_l = wi2_h + 3 * D2 * D2;
    u16* wh2_h = wi2_l + 3 * D2 * D2;
    u16* wh2_l = wh2_h + 3 * D2 * D2;
    int* cnt   = (int*)(wh2_l + 3 * D2 * D2);
    int* off   = cnt + NN;
    int* cur   = off + NN + 1;
    int* elist = cur + NN;
    unsigned* pool = (unsigned*)(elist + NE);

    // ---- CSR + prep + pad + pool init ----
    hipMemsetAsync(cnt, 0, NN * sizeof(int), stream);
    count_k<<<(NE + 255) / 256, 256, 0, stream>>>(dst, cnt);
    scan_k<<<1, 1024, 0, stream>>>(cnt, off, cur);
    fill_k<<<(NE + 255) / 256, 256, 0, stream>>>(src, dst, cur, elist);
    {
        int total = 3 * D1 * D1 + 3 * D2 * D2 + 2 * 3 * D1 * D1 + 2 * 3 * D2 * D2 + NN * D1;
        prep_k<<<(total + 255) / 256, 256, 0, stream>>>(
            w1, w2, wih1, whh1, wih2, whh2, x_in,
            w1t_h, w1t_l, w2t_h, w2t_l, wi1_h, wi1_l, wh1_h, wh1_l,
            wi2_h, wi2_l, wh2_h, wh2_l, xA_h[0], xA_l[0]);
    }
    pad_k<<<(NN * 128 + 255) / 256, 256, 0, stream>>>(xB_h[0], xB_l[0]);
    pool_init_k<<<(NG * D2 + 255) / 256, 256, 0, stream>>>(pool);

    const int MT = (NN + 127) / 128;  // 79

    // ---------------- layer 1 (C = 128) ----------------
    int cb = 0;
    for (int it = 0; it < 3; ++it) {
        const int C = D1;
        mgemm_k<<<dim3(C / 128, MT), 256, 0, stream>>>(
            xA_h[cb], xA_l[cb], w1t_h + it * C * C, w1t_l + it * C * C,
            mbuf, NN, C, C);
        gather_k<D1><<<(NN * (D1 / 4) + 255) / 256, 256, 0, stream>>>(
            mbuf, off, elist, a_h, a_l);
        if (it < 2) {
            gru_k<0, 128><<<dim3(3 * C / 96, MT), 256, 0, stream>>>(
                a_h, a_l, xA_h[cb], xA_l[cb], wi1_h, wi1_l, wh1_h, wh1_l,
                bih1, bhh1, xA_h[cb ^ 1], xA_l[cb ^ 1], nullptr, nullptr, NN, C);
            cb ^= 1;
        } else {  // relu + pad -> xB[0]
            gru_k<1, 256><<<dim3(3 * C / 96, MT), 256, 0, stream>>>(
                a_h, a_l, xA_h[cb], xA_l[cb], wi1_h, wi1_l, wh1_h, wh1_l,
                bih1, bhh1, xB_h[0], xB_l[0], nullptr, nullptr, NN, C);
        }
    }

    // ---------------- layer 2 (C = 256) ----------------
    cb = 0;
    for (int it = 0; it < 3; ++it) {
        const int C = D2;
        mgemm_k<<<dim3(C / 128, MT), 256, 0, stream>>>(
            xB_h[cb], xB_l[cb], w2t_h + it * C * C, w2t_l + it * C * C,
            mbuf, NN, C, C);
        gather_k<D2><<<(NN * (D2 / 4) + 255) / 256, 256, 0, stream>>>(
            mbuf, off, elist, a_h, a_l);
        if (it < 2) {
            gru_k<0, 256><<<dim3(3 * C / 96, MT), 256, 0, stream>>>(
                a_h, a_l, xB_h[cb], xB_l[cb], wi2_h, wi2_l, wh2_h, wh2_l,
                bih2, bhh2, xB_h[cb ^ 1], xB_l[cb ^ 1], nullptr, nullptr, NN, C);
            cb ^= 1;
        } else {  // final: fused segment-max pool
            gru_k<2, 256><<<dim3(3 * C / 96, MT), 256, 0, stream>>>(
                a_h, a_l, xB_h[cb], xB_l[cb], wi2_h, wi2_l, wh2_h, wh2_l,
                bih2, bhh2, nullptr, nullptr, batch, pool, NN, C);
        }
    }

    fc_k<<<1, 512, 0, stream>>>(pool, fcw, fcb, out);
}